// Round 13
// baseline (103.842 us; speedup 1.0000x reference)
//
#include <hip/hip_runtime.h>
#include <hip/hip_bf16.h>
#include <stdint.h>

#define SEQ   2048
#define NHEAD 32
#define HDIM  128
#define RS    (NHEAD * HDIM)   // 4096 floats: row stride in (b,s,h,d) layout
#define KVBLK 64
#define NTILES (SEQ / KVBLK)   // 32 kv tiles
#define TILE_BYTES 16384       // 16 KB fragment-image per tile (K or V)
#define IMG_BYTES ((size_t)NHEAD * NTILES * TILE_BYTES)   // 16 MB per tensor image

typedef float  f32x16 __attribute__((ext_vector_type(16)));
typedef __bf16 bf16x8 __attribute__((ext_vector_type(8)));
typedef uint32_t u32;

__device__ __forceinline__ unsigned short f2bf(float f) {
  unsigned u = __builtin_bit_cast(unsigned, f);
  u += 0x7fffu + ((u >> 16) & 1u);           // round-to-nearest-even
  return (unsigned short)(u >> 16);
}

__device__ __forceinline__ u32 packbf(float a, float b) {
  __bf16 x = (__bf16)a, y = (__bf16)b;
  unsigned short ux = __builtin_bit_cast(unsigned short, x);
  unsigned short uy = __builtin_bit_cast(unsigned short, y);
  return (u32)ux | ((u32)uy << 16);
}

// ---------------- pre-pass: build MFMA-fragment images (verbatim R9, verified) ----------------
__global__ __launch_bounds__(256) void prepass_kernel(
    const float* __restrict__ K, const float* __restrict__ V,
    char* __restrict__ wsK, char* __restrict__ wsV) {
  const int tid = threadIdx.x;
  const int t   = blockIdx.x & (NTILES - 1);
  const int h   = blockIdx.x >> 5;
  const int kv0 = t * KVBLK;
  char* kd = wsK + (size_t)(h * NTILES + t) * TILE_BYTES;
  char* vd = wsV + (size_t)(h * NTILES + t) * TILE_BYTES;

  {
    const int c  = tid & 15;
    const int kr = tid >> 4;
#pragma unroll
    for (int ki = 0; ki < 4; ++ki) {
      const int kk = kr + ki * 16;
      const float* kp = K + (size_t)(kv0 + kk) * RS + h * HDIM + c * 8;
      float4 x0 = *(const float4*)kp;
      float4 x1 = *(const float4*)(kp + 4);
      uint32_t u0 = f2bf(x0.x) | ((uint32_t)f2bf(x0.y) << 16);
      uint32_t u1 = f2bf(x0.z) | ((uint32_t)f2bf(x0.w) << 16);
      uint32_t u2 = f2bf(x1.x) | ((uint32_t)f2bf(x1.y) << 16);
      uint32_t u3 = f2bf(x1.z) | ((uint32_t)f2bf(x1.w) << 16);
      const int kt = kk >> 5, nn = kk & 31, ks = c >> 1, hh = c & 1;
      const uint32_t byte = (uint32_t)((kt * 8 + ks) * 1024 + (hh * 32 + nn) * 16);
      *(uint4*)(kd + byte) = make_uint4(u0, u1, u2, u3);
    }
  }
  {
    const int d0  = (tid & 31) * 4;
    const int kk0 = (tid >> 5) * 8;
    float vv[8][4];
#pragma unroll
    for (int r = 0; r < 8; ++r) {
      const float* vp = V + (size_t)(kv0 + kk0 + r) * RS + h * HDIM + d0;
      float4 x = *(const float4*)vp;
      vv[r][0] = x.x; vv[r][1] = x.y; vv[r][2] = x.z; vv[r][3] = x.w;
    }
    const int s = kk0 >> 4, hh = (kk0 >> 3) & 1;
#pragma unroll
    for (int i = 0; i < 4; ++i) {
      const int d = d0 + i;
      uint32_t p0 = f2bf(vv[0][i]) | ((uint32_t)f2bf(vv[1][i]) << 16);
      uint32_t p1 = f2bf(vv[2][i]) | ((uint32_t)f2bf(vv[3][i]) << 16);
      uint32_t p2 = f2bf(vv[4][i]) | ((uint32_t)f2bf(vv[5][i]) << 16);
      uint32_t p3 = f2bf(vv[6][i]) | ((uint32_t)f2bf(vv[7][i]) << 16);
      const int nt = d >> 5;
      const uint32_t byte = (uint32_t)((s * 4 + nt) * 1024 + (hh * 32 + (d & 31)) * 16);
      *(uint4*)(vd + byte) = make_uint4(p0, p1, p2, p3);
    }
  }
}

// ================= shared per-wave flash body (R9-verified) =================
// Computes accO/m_run/l over tiles {t0, t0+step, ...} < ntile for one (head, qi).
#define FLASH_BODY(T0, STEP)                                                     \
  for (int t = (T0); t < ntile; t += (STEP)) {                                   \
    const char* kb = kimg + (size_t)t * TILE_BYTES;                              \
    uint4 kld[16];                                                               \
    _Pragma("unroll")                                                            \
    for (int i = 0; i < 16; ++i) kld[i] = *(const uint4*)(kb + i * 1024);        \
    f32x16 sc[2];                                                                \
    __builtin_amdgcn_s_setprio(1);                                               \
    _Pragma("unroll")                                                            \
    for (int kt = 0; kt < 2; ++kt) {                                             \
      f32x16 acc = (f32x16)(0.f);                                                \
      _Pragma("unroll")                                                          \
      for (int ks = 0; ks < 8; ++ks) {                                           \
        bf16x8 kf = __builtin_bit_cast(bf16x8, kld[kt * 8 + ks]);                \
        acc = __builtin_amdgcn_mfma_f32_32x32x16_bf16(kf, bq[ks], acc, 0, 0, 0); \
      }                                                                          \
      sc[kt] = acc;                                                              \
    }                                                                            \
    __builtin_amdgcn_s_setprio(0);                                               \
    const char* vb = vimg + (size_t)t * TILE_BYTES;                              \
    uint4 vld[16];                                                               \
    _Pragma("unroll")                                                            \
    for (int i = 0; i < 16; ++i) vld[i] = *(const uint4*)(vb + i * 1024);        \
    if (t == ntile - 1) {                                                        \
      const int kv0 = t * KVBLK;                                                 \
      _Pragma("unroll")                                                          \
      for (int kt = 0; kt < 2; ++kt)                                             \
        _Pragma("unroll")                                                        \
        for (int r = 0; r < 16; ++r) {                                           \
          const int keyg = kv0 + kt * 32 + (r & 3) + 8 * (r >> 2) + 4 * hh;      \
          if (keyg > qrow) sc[kt][r] = -1e30f;                                   \
        }                                                                        \
    }                                                                            \
    float tm[16];                                                                \
    _Pragma("unroll")                                                            \
    for (int r = 0; r < 16; ++r) tm[r] = fmaxf(sc[0][r], sc[1][r]);              \
    _Pragma("unroll")                                                            \
    for (int r = 0; r < 8; ++r) tm[r] = fmaxf(tm[r], tm[r + 8]);                 \
    _Pragma("unroll")                                                            \
    for (int r = 0; r < 4; ++r) tm[r] = fmaxf(tm[r], tm[r + 4]);                 \
    float mx = fmaxf(fmaxf(tm[0], tm[1]), fmaxf(tm[2], tm[3]));                  \
    mx = fmaxf(mx, __shfl_xor(mx, 32, 64));                                      \
    if (__any(mx - m_run > 11.0f)) {                                             \
      const float mn = fmaxf(m_run, mx);                                         \
      const float al = exp2f(m_run - mn);                                        \
      m_run = mn;                                                                \
      l_part *= al;                                                              \
      _Pragma("unroll")                                                          \
      for (int r = 0; r < 16; ++r) {                                             \
        const float ar = __shfl(al, (r & 3) + 8 * (r >> 2) + 4 * hh, 64);        \
        _Pragma("unroll")                                                        \
        for (int nt = 0; nt < 4; ++nt) accO[nt][r] *= ar;                        \
      }                                                                          \
    }                                                                            \
    float ls = 0.f;                                                              \
    _Pragma("unroll")                                                            \
    for (int kt = 0; kt < 2; ++kt)                                               \
      _Pragma("unroll")                                                          \
      for (int r = 0; r < 16; ++r) {                                             \
        const float p = exp2f(sc[kt][r] - m_run);                                \
        sc[kt][r] = p;                                                           \
        ls += p;                                                                 \
      }                                                                          \
    l_part += ls;                                                                \
    u32 ua[2][4], ub[2][4];                                                      \
    _Pragma("unroll")                                                            \
    for (int kt = 0; kt < 2; ++kt)                                               \
      _Pragma("unroll")                                                          \
      for (int i = 0; i < 4; ++i) {                                              \
        ua[kt][i] = packbf(sc[kt][4 * i],     sc[kt][4 * i + 1]);                \
        ub[kt][i] = packbf(sc[kt][4 * i + 2], sc[kt][4 * i + 3]);                \
      }                                                                          \
    u32 ra[2][2], rb[2][2];                                                      \
    _Pragma("unroll")                                                            \
    for (int kt = 0; kt < 2; ++kt)                                               \
      _Pragma("unroll")                                                          \
      for (int q = 0; q < 2; ++q) {                                              \
        ra[kt][q] = __shfl_xor(hh ? ua[kt][2 * q] : ua[kt][2 * q + 1], 32, 64);  \
        rb[kt][q] = __shfl_xor(hh ? ub[kt][2 * q] : ub[kt][2 * q + 1], 32, 64);  \
      }                                                                          \
    __builtin_amdgcn_s_setprio(1);                                               \
    _Pragma("unroll")                                                            \
    for (int s = 0; s < 4; ++s) {                                                \
      const int kt = s >> 1, q = s & 1;                                          \
      u32 af32[4];                                                               \
      af32[0] = hh ? ra[kt][q] : ua[kt][2 * q];                                  \
      af32[1] = hh ? rb[kt][q] : ub[kt][2 * q];                                  \
      af32[2] = hh ? ua[kt][2 * q + 1] : ra[kt][q];                              \
      af32[3] = hh ? ub[kt][2 * q + 1] : rb[kt][q];                              \
      bf16x8 af = __builtin_bit_cast(bf16x8, *(uint4*)af32);                     \
      _Pragma("unroll")                                                          \
      for (int nt = 0; nt < 4; ++nt) {                                           \
        bf16x8 vf = __builtin_bit_cast(bf16x8, vld[s * 4 + nt]);                 \
        accO[nt] = __builtin_amdgcn_mfma_f32_32x32x16_bf16(af, vf, accO[nt], 0, 0, 0); \
      }                                                                          \
    }                                                                            \
    __builtin_amdgcn_s_setprio(0);                                               \
  }

#define FLASH_PROLOG(GRID_DIV)                                                   \
  const int lane = threadIdx.x;                                                  \
  const int n    = lane & 31;                                                    \
  const int hh   = lane >> 5;                                                    \
  const float qscale = 0.088388347648318447f * 1.4426950408889634f;              \
  bf16x8 bq[8];                                                                  \
  {                                                                              \
    const float* qp = Q + (size_t)qrow * RS + head * HDIM + hh * 8;              \
    _Pragma("unroll")                                                            \
    for (int ks = 0; ks < 8; ++ks) {                                             \
      float4 v0 = *(const float4*)(qp + ks * 16);                                \
      float4 v1 = *(const float4*)(qp + ks * 16 + 4);                            \
      bf16x8 a;                                                                  \
      a[0] = (__bf16)(v0.x * qscale); a[1] = (__bf16)(v0.y * qscale);            \
      a[2] = (__bf16)(v0.z * qscale); a[3] = (__bf16)(v0.w * qscale);            \
      a[4] = (__bf16)(v1.x * qscale); a[5] = (__bf16)(v1.y * qscale);            \
      a[6] = (__bf16)(v1.z * qscale); a[7] = (__bf16)(v1.w * qscale);            \
      bq[ks] = a;                                                                \
    }                                                                            \
  }                                                                              \
  f32x16 accO[4];                                                                \
  _Pragma("unroll")                                                              \
  for (int i = 0; i < 4; ++i) accO[i] = (f32x16)(0.f);                           \
  float m_run  = -1e30f;                                                         \
  float l_part = 0.f;                                                            \
  const char* kimg = wsK + (size_t)head * NTILES * TILE_BYTES + lane * 16;       \
  const char* vimg = wsV + (size_t)head * NTILES * TILE_BYTES + lane * 16;

// ---------------- split main: 2 single-wave blocks per q-unit (even/odd tiles) ----------------
__global__ __launch_bounds__(64, 2) void fattn_split(
    const float* __restrict__ Q, const char* __restrict__ wsK,
    const char* __restrict__ wsV, float* __restrict__ wsO,
    float* __restrict__ wsM, float* __restrict__ wsL) {
  const int bid  = blockIdx.x;          // 0..4095; bid&7 = XCD
  const int k    = bid >> 3;            // 0..511
  const int head = (bid & 7) * 4 + (k & 3);
  const int r_   = k >> 2;              // 0..127: (qi, half), big work first
  const int qi   = 63 - (r_ >> 1);
  const int half = r_ & 1;
  const int ntile = (qi >> 1) + 1;
  const int qrow  = qi * 32 + (threadIdx.x & 31);

  FLASH_PROLOG(8)
  FLASH_BODY(half, 2)

  // ---- partial epilogue: unnormalized O, per-row m & l ----
  const float lf   = l_part + __shfl_xor(l_part, 32, 64);
  const int   unit = (head * 64 + qi) * 2 + half;
  float* po = wsO + (size_t)unit * 4096;
#pragma unroll
  for (int r = 0; r < 16; ++r) {
    const int row = (r & 3) + 8 * (r >> 2) + 4 * hh;
#pragma unroll
    for (int nt = 0; nt < 4; ++nt) po[row * 128 + nt * 32 + n] = accO[nt][r];
  }
  if (lane < 32) { wsM[unit * 32 + lane] = m_run; wsL[unit * 32 + lane] = lf; }
}

// ---------------- combine: merge the two partials per q-unit ----------------
__global__ __launch_bounds__(256) void combine_kernel(
    const float* __restrict__ wsO, const float* __restrict__ wsM,
    const float* __restrict__ wsL, float* __restrict__ O) {
  const int bid  = blockIdx.x;          // 0..2047
  const int head = bid >> 6;
  const int qi   = bid & 63;
  const int t    = threadIdx.x;         // 256 thr x 16 f32 = 4096 elems
  const int row  = t >> 3;
  const int col  = (t & 7) * 16;

  const int ua = (head * 64 + qi) * 2;
  const float m_a = wsM[ua * 32 + row],       l_a = wsL[ua * 32 + row];
  const float m_b = wsM[(ua + 1) * 32 + row], l_b = wsL[(ua + 1) * 32 + row];
  const float m_f = fmaxf(m_a, m_b);
  const float aa  = exp2f(m_a - m_f);
  const float ab  = exp2f(m_b - m_f);
  const float inv = 1.0f / (l_a * aa + l_b * ab);

  const float* pa = wsO + (size_t)ua * 4096 + row * 128 + col;
  const float* pb = pa + 4096;
  float* po = O + (size_t)(qi * 32 + row) * RS + head * HDIM + col;
#pragma unroll
  for (int i = 0; i < 4; ++i) {
    float4 xa = *(const float4*)(pa + i * 4);
    float4 xb = *(const float4*)(pb + i * 4);
    float4 y;
    y.x = (xa.x * aa + xb.x * ab) * inv;
    y.y = (xa.y * aa + xb.y * ab) * inv;
    y.z = (xa.z * aa + xb.z * ab) * inv;
    y.w = (xa.w * aa + xb.w * ab) * inv;
    *(float4*)(po + i * 4) = y;
  }
}

// ---------------- fallback full-range main (R9, 82 us verified) ----------------
__global__ __launch_bounds__(64, 2) void fattn_full(
    const float* __restrict__ Q, const char* __restrict__ wsK,
    const char* __restrict__ wsV, float* __restrict__ O) {
  const int bid  = blockIdx.x;          // 0..2047
  const int k    = bid >> 3;
  const int head = (bid & 7) * 4 + (k & 3);
  const int qi   = 63 - (k >> 2);
  const int ntile = (qi >> 1) + 1;
  const int qrow  = qi * 32 + (threadIdx.x & 31);

  FLASH_PROLOG(8)
  FLASH_BODY(0, 1)

  const float lf  = l_part + __shfl_xor(l_part, 32, 64);
  const float inv = 1.0f / lf;
  float* ob = O + (size_t)(qi * 32) * RS + head * HDIM;
#pragma unroll
  for (int r = 0; r < 16; ++r) {
    const int m = (r & 3) + 8 * (r >> 2) + 4 * hh;
    const float im = __shfl(inv, m, 64);
#pragma unroll
    for (int nt = 0; nt < 4; ++nt)
      ob[(size_t)m * RS + nt * 32 + n] = accO[nt][r] * im;
  }
}

extern "C" void kernel_launch(void* const* d_in, const int* in_sizes, int n_in,
                              void* d_out, int out_size, void* d_ws, size_t ws_size,
                              hipStream_t stream) {
  const float* q = (const float*)d_in[0];
  const float* k = (const float*)d_in[1];
  const float* v = (const float*)d_in[2];
  float* o = (float*)d_out;
  char* wsK = (char*)d_ws;
  char* wsV = wsK + IMG_BYTES;

  const size_t oO = 2 * IMG_BYTES;                       // partial O: 4096 x 16 KB
  const size_t oM = oO + (size_t)4096 * 4096 * 4;        // m: 4096 x 32 f32
  const size_t oL = oM + (size_t)4096 * 32 * 4;
  const size_t need = oL + (size_t)4096 * 32 * 4;

  hipLaunchKernelGGL(prepass_kernel, dim3(NHEAD * NTILES), dim3(256), 0, stream,
                     k, v, wsK, wsV);
  if (ws_size >= need) {
    float* wsO = (float*)((char*)d_ws + oO);
    float* wsM = (float*)((char*)d_ws + oM);
    float* wsL = (float*)((char*)d_ws + oL);
    hipLaunchKernelGGL(fattn_split, dim3(4096), dim3(64), 0, stream,
                       q, wsK, wsV, wsO, wsM, wsL);
    hipLaunchKernelGGL(combine_kernel, dim3(NHEAD * 64), dim3(256), 0, stream,
                       wsO, wsM, wsL, o);
  } else {
    hipLaunchKernelGGL(fattn_full, dim3(2048), dim3(64), 0, stream, q, wsK, wsV, o);
  }
}

// Round 14
// 89.227 us; speedup vs baseline: 1.1638x; 1.1638x over previous
//
#include <hip/hip_runtime.h>
#include <hip/hip_bf16.h>
#include <stdint.h>

#define SEQ   2048
#define NHEAD 32
#define HDIM  128
#define RS    (NHEAD * HDIM)   // 4096 floats: row stride in (b,s,h,d) layout
#define KVBLK 64
#define QBLK  128
#define NTILES (SEQ / KVBLK)   // 32 kv tiles
#define TILE_BYTES 16384       // 16 KB fragment-image per tile (K or V)

typedef float  f32x16 __attribute__((ext_vector_type(16)));
typedef __bf16 bf16x8 __attribute__((ext_vector_type(8)));
typedef uint32_t u32;

__device__ __forceinline__ unsigned short f2bf(float f) {
  unsigned u = __builtin_bit_cast(unsigned, f);
  u += 0x7fffu + ((u >> 16) & 1u);           // round-to-nearest-even
  return (unsigned short)(u >> 16);
}

__device__ __forceinline__ u32 packbf(float a, float b) {
  __bf16 x = (__bf16)a, y = (__bf16)b;
  unsigned short ux = __builtin_bit_cast(unsigned short, x);
  unsigned short uy = __builtin_bit_cast(unsigned short, y);
  return (u32)ux | ((u32)uy << 16);
}

__device__ __forceinline__ void gld16(const void* g, void* l) {
  // async global->LDS, 16B/lane; LDS dest wave-uniform base (HW adds lane*16)
  __builtin_amdgcn_global_load_lds(
      (const __attribute__((address_space(1))) unsigned int*)g,
      (__attribute__((address_space(3))) unsigned int*)l, 16, 0, 0);
}

// ---------------- pre-pass: MFMA-fragment images (verbatim R9, verified) ----------------
// K image chunk (kt,ks) [1KB]: slot lane=hh*32+n (16B) = K[kv0+kt*32+n][d=ks*16+hh*8 .. +7]
// V image chunk (s,nt)  [1KB]: slot lane=hh*32+n (16B) = V^T[d=nt*32+n][keys s*16+hh*8 .. +7]
__global__ __launch_bounds__(256) void prepass_kernel(
    const float* __restrict__ K, const float* __restrict__ V,
    char* __restrict__ wsK, char* __restrict__ wsV) {
  const int tid = threadIdx.x;
  const int t   = blockIdx.x & (NTILES - 1);
  const int h   = blockIdx.x >> 5;
  const int kv0 = t * KVBLK;
  char* kd = wsK + (size_t)(h * NTILES + t) * TILE_BYTES;
  char* vd = wsV + (size_t)(h * NTILES + t) * TILE_BYTES;

  {
    const int c  = tid & 15;    // d-chunk: d0 = c*8 -> ks = c>>1, hh = c&1
    const int kr = tid >> 4;    // 0..15
#pragma unroll
    for (int ki = 0; ki < 4; ++ki) {
      const int kk = kr + ki * 16;
      const float* kp = K + (size_t)(kv0 + kk) * RS + h * HDIM + c * 8;
      float4 x0 = *(const float4*)kp;
      float4 x1 = *(const float4*)(kp + 4);
      uint32_t u0 = f2bf(x0.x) | ((uint32_t)f2bf(x0.y) << 16);
      uint32_t u1 = f2bf(x0.z) | ((uint32_t)f2bf(x0.w) << 16);
      uint32_t u2 = f2bf(x1.x) | ((uint32_t)f2bf(x1.y) << 16);
      uint32_t u3 = f2bf(x1.z) | ((uint32_t)f2bf(x1.w) << 16);
      const int kt = kk >> 5, nn = kk & 31, ks = c >> 1, hh = c & 1;
      const uint32_t byte = (uint32_t)((kt * 8 + ks) * 1024 + (hh * 32 + nn) * 16);
      *(uint4*)(kd + byte) = make_uint4(u0, u1, u2, u3);
    }
  }
  {
    const int d0  = (tid & 31) * 4;
    const int kk0 = (tid >> 5) * 8;
    float vv[8][4];
#pragma unroll
    for (int r = 0; r < 8; ++r) {
      const float* vp = V + (size_t)(kv0 + kk0 + r) * RS + h * HDIM + d0;
      float4 x = *(const float4*)vp;
      vv[r][0] = x.x; vv[r][1] = x.y; vv[r][2] = x.z; vv[r][3] = x.w;
    }
    const int s = kk0 >> 4, hh = (kk0 >> 3) & 1;
#pragma unroll
    for (int i = 0; i < 4; ++i) {
      const int d = d0 + i;
      uint32_t p0 = f2bf(vv[0][i]) | ((uint32_t)f2bf(vv[1][i]) << 16);
      uint32_t p1 = f2bf(vv[2][i]) | ((uint32_t)f2bf(vv[3][i]) << 16);
      uint32_t p2 = f2bf(vv[4][i]) | ((uint32_t)f2bf(vv[5][i]) << 16);
      uint32_t p3 = f2bf(vv[6][i]) | ((uint32_t)f2bf(vv[7][i]) << 16);
      const int nt = d >> 5;
      const uint32_t byte = (uint32_t)((s * 4 + nt) * 1024 + (hh * 32 + (d & 31)) * 16);
      *(uint4*)(vd + byte) = make_uint4(p0, p1, p2, p3);
    }
  }
}

// -------- main: R6 schedule (4 waves, QBLK=128, dbuf LDS, complement pairing) --------
// -------- with fragment-image LDS: conflict-free ds_read_b128, no XOR math   --------
__global__ __launch_bounds__(256, 2) void fattn_main(
    const float* __restrict__ Q, const char* __restrict__ wsK,
    const char* __restrict__ wsV, float* __restrict__ O) {
  const int tid  = threadIdx.x;
  const int w    = tid >> 6;      // wave 0..3
  const int lane = tid & 63;
  const int n    = lane & 31;
  const int hh   = lane >> 5;

  // XCD swizzle + complement pairing: (bid, bid+256) land on the same CU and
  // their qb values sum to 15 -> exactly 34 kv-tile-iters per CU.
  const int bid  = blockIdx.x;          // 0..511
  const int b2   = bid & 255;
  const int vid  = (b2 & 7) * 32 + (b2 >> 3);
  const int head = vid >> 3;
  const int jj   = vid & 7;
  const int qb   = (bid < 256) ? (15 - jj) : jj;
  const int q0   = qb * QBLK;
  const int ntile  = 2 * qb + 2;
  const int diag_t = 2 * qb + (w >> 1);   // wave's straddling tile

  __shared__ __align__(16) char smem[65536];   // 2 x (16KB K-image + 16KB V-image)
  auto Kbuf = [&](int b) { return smem + b * 32768; };
  auto Vbuf = [&](int b) { return smem + b * 32768 + 16384; };

  const float qscale = 0.088388347648318447f * 1.4426950408889634f; // 1/sqrt(D)*log2(e)
  const int qrow = q0 + w * 32 + n;

  // Q B-fragments: bq[ks] holds Q[qrow][ks*16 + hh*8 + j] * qscale
  bf16x8 bq[8];
  {
    const float* qp = Q + (size_t)qrow * RS + head * HDIM + hh * 8;
#pragma unroll
    for (int ks = 0; ks < 8; ++ks) {
      float4 v0 = *(const float4*)(qp + ks * 16);
      float4 v1 = *(const float4*)(qp + ks * 16 + 4);
      bf16x8 a;
      a[0] = (__bf16)(v0.x * qscale); a[1] = (__bf16)(v0.y * qscale);
      a[2] = (__bf16)(v0.z * qscale); a[3] = (__bf16)(v0.w * qscale);
      a[4] = (__bf16)(v1.x * qscale); a[5] = (__bf16)(v1.y * qscale);
      a[6] = (__bf16)(v1.z * qscale); a[7] = (__bf16)(v1.w * qscale);
      bq[ks] = a;
    }
  }

  f32x16 accO[4];
#pragma unroll
  for (int i = 0; i < 4; ++i) accO[i] = (f32x16)(0.f);
  float m_run  = -1e30f;
  float l_part = 0.f;

  const char* kbase = wsK + (size_t)head * NTILES * TILE_BYTES;
  const char* vbase = wsV + (size_t)head * NTILES * TILE_BYTES;
  const bool  doK   = (w < 2);
  const char* sbase = doK ? kbase : vbase;
  const int   half  = (w & 1) * 8192;

  auto stage = [&](int buf, int t) {   // each wave stages half of K-image or V-image
    const char* src = sbase + (size_t)t * TILE_BYTES + half + lane * 16;
    char* dst = (doK ? Kbuf(buf) : Vbuf(buf)) + half;
#pragma unroll
    for (int i = 0; i < 8; ++i) gld16(src + i * 1024, dst + i * 1024);
  };

  stage(0, 0);
  asm volatile("s_waitcnt vmcnt(0)" ::: "memory");
  __builtin_amdgcn_sched_barrier(0);
  __syncthreads();

  const int lofs = lane * 16;   // fragment slot within each 1KB chunk

  for (int t = 0; t < ntile; ++t) {
    const int cur = t & 1;
    if (t + 1 < ntile) stage(cur ^ 1, t + 1);   // async prefetch into other buffer

    if (t <= diag_t) {
      const char* Kc = Kbuf(cur) + lofs;
      const char* Vc = Vbuf(cur) + lofs;

      // ---- S^T = K Q^T : frag (kt,ks) at chunk (kt*8+ks)*1024, conflict-free b128 ----
      f32x16 sc[2];
      __builtin_amdgcn_s_setprio(1);
#pragma unroll
      for (int kt = 0; kt < 2; ++kt) {
        f32x16 acc = (f32x16)(0.f);
#pragma unroll
        for (int ks = 0; ks < 8; ++ks) {
          bf16x8 kf = *(const bf16x8*)(Kc + (kt * 8 + ks) * 1024);
          acc = __builtin_amdgcn_mfma_f32_32x32x16_bf16(kf, bq[ks], acc, 0, 0, 0);
        }
        sc[kt] = acc;
      }
      __builtin_amdgcn_s_setprio(0);

      // ---- causal mask (straddling tile only) ----
      if (t == diag_t) {
        const int kv0 = t * KVBLK;
#pragma unroll
        for (int kt = 0; kt < 2; ++kt)
#pragma unroll
          for (int r = 0; r < 16; ++r) {
            const int keyg = kv0 + kt * 32 + (r & 3) + 8 * (r >> 2) + 4 * hh;
            if (keyg > qrow) sc[kt][r] = -1e30f;
          }
      }

      // ---- row max: pairwise tree + cross-half swap ----
      float tm[16];
#pragma unroll
      for (int r = 0; r < 16; ++r) tm[r] = fmaxf(sc[0][r], sc[1][r]);
#pragma unroll
      for (int r = 0; r < 8; ++r) tm[r] = fmaxf(tm[r], tm[r + 8]);
#pragma unroll
      for (int r = 0; r < 4; ++r) tm[r] = fmaxf(tm[r], tm[r + 4]);
      float mx = fmaxf(fmaxf(tm[0], tm[1]), fmaxf(tm[2], tm[3]));
      mx = fmaxf(mx, __shfl_xor(mx, 32, 64));

      // ---- defer-max (T13): rare rescale ----
      if (__any(mx - m_run > 11.0f)) {
        const float mn = fmaxf(m_run, mx);
        const float al = exp2f(m_run - mn);
        m_run = mn;
        l_part *= al;
#pragma unroll
        for (int r = 0; r < 16; ++r) {
          const float ar = __shfl(al, (r & 3) + 8 * (r >> 2) + 4 * hh, 64);
#pragma unroll
          for (int nt = 0; nt < 4; ++nt) accO[nt][r] *= ar;
        }
      }

      // ---- P = exp2(S - m_run); own-half row sum ----
      float ls = 0.f;
#pragma unroll
      for (int kt = 0; kt < 2; ++kt)
#pragma unroll
        for (int r = 0; r < 16; ++r) {
          const float p = exp2f(sc[kt][r] - m_run);
          sc[kt][r] = p;
          ls += p;
        }
      l_part += ls;

      // ---- pack + cross-half exchange (verified R6 algebra) ----
      u32 ua[2][4], ub[2][4];
#pragma unroll
      for (int kt = 0; kt < 2; ++kt)
#pragma unroll
        for (int i = 0; i < 4; ++i) {
          ua[kt][i] = packbf(sc[kt][4 * i],     sc[kt][4 * i + 1]);
          ub[kt][i] = packbf(sc[kt][4 * i + 2], sc[kt][4 * i + 3]);
        }
      u32 ra[2][2], rb[2][2];
#pragma unroll
      for (int kt = 0; kt < 2; ++kt)
#pragma unroll
        for (int q = 0; q < 2; ++q) {
          ra[kt][q] = __shfl_xor(hh ? ua[kt][2 * q] : ua[kt][2 * q + 1], 32, 64);
          rb[kt][q] = __shfl_xor(hh ? ub[kt][2 * q] : ub[kt][2 * q + 1], 32, 64);
        }

      // ---- O += P V : V frag (s,nt) at chunk (s*4+nt)*1024 ----
      __builtin_amdgcn_s_setprio(1);
#pragma unroll
      for (int s = 0; s < 4; ++s) {
        const int kt = s >> 1, q = s & 1;
        u32 af32[4];
        af32[0] = hh ? ra[kt][q] : ua[kt][2 * q];
        af32[1] = hh ? rb[kt][q] : ub[kt][2 * q];
        af32[2] = hh ? ua[kt][2 * q + 1] : ra[kt][q];
        af32[3] = hh ? ub[kt][2 * q + 1] : rb[kt][q];
        bf16x8 af = __builtin_bit_cast(bf16x8, *(uint4*)af32);
#pragma unroll
        for (int nt = 0; nt < 4; ++nt) {
          bf16x8 vf = *(const bf16x8*)(Vc + (s * 4 + nt) * 1024);
          accO[nt] = __builtin_amdgcn_mfma_f32_32x32x16_bf16(af, vf, accO[nt], 0, 0, 0);
        }
      }
      __builtin_amdgcn_s_setprio(0);
    }

    // explicit drain (race-proven R5 skeleton): prefetch landed + LDS reads retired
    asm volatile("s_waitcnt vmcnt(0) lgkmcnt(0)" ::: "memory");
    __builtin_amdgcn_sched_barrier(0);
    __syncthreads();
  }

  // ---- epilogue: combine halves, O / l ----
  const float lf  = l_part + __shfl_xor(l_part, 32, 64);
  const float inv = 1.0f / lf;
  float* ob = O + (size_t)(q0 + w * 32) * RS + head * HDIM;
#pragma unroll
  for (int r = 0; r < 16; ++r) {
    const int m = (r & 3) + 8 * (r >> 2) + 4 * hh;
    const float im = __shfl(inv, m, 64);
#pragma unroll
    for (int nt = 0; nt < 4; ++nt)
      ob[(size_t)m * RS + nt * 32 + n] = accO[nt][r] * im;
  }
}

extern "C" void kernel_launch(void* const* d_in, const int* in_sizes, int n_in,
                              void* d_out, int out_size, void* d_ws, size_t ws_size,
                              hipStream_t stream) {
  const float* q = (const float*)d_in[0];
  const float* k = (const float*)d_in[1];
  const float* v = (const float*)d_in[2];
  float* o = (float*)d_out;
  char* wsK = (char*)d_ws;
  char* wsV = wsK + (size_t)NHEAD * NTILES * TILE_BYTES;
  hipLaunchKernelGGL(prepass_kernel, dim3(NHEAD * NTILES), dim3(256), 0, stream,
                     k, v, wsK, wsV);
  hipLaunchKernelGGL(fattn_main, dim3(512), dim3(256), 0, stream, q, wsK, wsV, o);
}